// Round 7
// baseline (684.723 us; speedup 1.0000x reference)
//
#include <hip/hip_runtime.h>
#include <math.h>

#define NV 204800
#define NE 409600
#define NG 512
#define V_PER 400
#define E_PER 800

#define BM 128   // rows per block in the projection GEMM
#define KT 32    // k-tile

// Wt column swizzle (float4-granular XOR of word-bit2 with word-bit5).
__device__ __forceinline__ int wswz(int j) { return j ^ (((j >> 5) & 1) << 2); }

// ---- Kernel 1: fused projection GEMM  y = x @ [W1 | We1[0:128]]  ----------
// Double-buffered LDS: global loads for tile t+1 issued before compute of t,
// ds_write after compute, ONE barrier per tile. Epilogue: cols 0-63 ->
// vertex MLP -> fv; cols 64-127 -> raw y2.
__global__ __launch_bounds__(256)
void k_proj(const float* __restrict__ x, const float* __restrict__ W1,
            const float* __restrict__ b1, const float* __restrict__ W2,
            const float* __restrict__ b2, const float* __restrict__ We1,
            float* __restrict__ fv, float* __restrict__ y2) {
  // buf b at smem + b*32768: xt[32][128] (16KB) then Wt[32][128] (16KB).
  // epilogue hs[128][65] (33.3KB) overlaps buf0 (+512B of buf1) after barrier.
  __shared__ __align__(16) char smem[66560];
  float (*hs)[65] = (float (*)[65])smem;
  __shared__ float W2s[64 * 8];

  const int tid = threadIdx.x;
  const long vb = (long)blockIdx.x * BM;

  if (tid < 128) ((float4*)W2s)[tid] = ((const float4*)W2)[tid];

  const int v = tid >> 1, h = tid & 1;      // staging: 2 threads per row
  const int jg = tid & 15, rg = tid >> 4;   // compute: 16 col-grps x 16 row-grps
  const int wb0 = wswz(jg * 8);
  const int wb1 = wswz(jg * 8 + 4);

  float4 px[4], pw[4];  // prefetch regs (x half-row; W1/We1 slabs)

  auto load_regs = [&](int t) {
    const float4* src = (const float4*)(x + (vb + v) * 128 + t * KT + h * 16);
    px[0] = src[0]; px[1] = src[1]; px[2] = src[2]; px[3] = src[3];
    pw[0] = ((const float4*)(W1 + t * KT * 64))[tid];
    pw[1] = ((const float4*)(W1 + t * KT * 64))[tid + 256];
    pw[2] = ((const float4*)(We1 + t * KT * 64))[tid];
    pw[3] = ((const float4*)(We1 + t * KT * 64))[tid + 256];
  };
  auto store_tile = [&](int b) {
    float (*xt)[BM] = (float (*)[BM])(smem + b * 32768);
    float (*Wt)[BM] = (float (*)[BM])(smem + b * 32768 + 16384);
    const int r = h * 16;
    xt[r + 0][v] = px[0].x; xt[r + 1][v] = px[0].y; xt[r + 2][v] = px[0].z; xt[r + 3][v] = px[0].w;
    xt[r + 4][v] = px[1].x; xt[r + 5][v] = px[1].y; xt[r + 6][v] = px[1].z; xt[r + 7][v] = px[1].w;
    xt[r + 8][v] = px[2].x; xt[r + 9][v] = px[2].y; xt[r +10][v] = px[2].z; xt[r +11][v] = px[2].w;
    xt[r +12][v] = px[3].x; xt[r +13][v] = px[3].y; xt[r +14][v] = px[3].z; xt[r +15][v] = px[3].w;
    #pragma unroll
    for (int q = 0; q < 2; ++q) {
      const int idx = tid + q * 256;
      const int kk = idx >> 4, j4 = idx & 15;
      *(float4*)&Wt[kk][wswz(j4 * 4)] = pw[q];
      *(float4*)&Wt[kk][wswz(64 + j4 * 4)] = pw[2 + q];
    }
  };

  float acc[8][8];
  #pragma unroll
  for (int i = 0; i < 8; ++i)
    #pragma unroll
    for (int j = 0; j < 8; ++j) acc[i][j] = 0.f;

  load_regs(0);
  store_tile(0);
  __syncthreads();

  #pragma unroll 1
  for (int t = 0; t < 4; ++t) {
    if (t < 3) load_regs(t + 1);          // in flight across the FMA phase
    const int b = t & 1;
    float (*xt)[BM] = (float (*)[BM])(smem + b * 32768);
    float (*Wt)[BM] = (float (*)[BM])(smem + b * 32768 + 16384);
    #pragma unroll
    for (int kk = 0; kk < KT; ++kk) {
      const float4 av0 = *(const float4*)&xt[kk][rg * 8];
      const float4 av1 = *(const float4*)&xt[kk][rg * 8 + 4];
      const float4 w0 = *(const float4*)&Wt[kk][wb0];
      const float4 w1 = *(const float4*)&Wt[kk][wb1];
      const float a[8] = {av0.x, av0.y, av0.z, av0.w, av1.x, av1.y, av1.z, av1.w};
      const float w[8] = {w0.x, w0.y, w0.z, w0.w, w1.x, w1.y, w1.z, w1.w};
      #pragma unroll
      for (int i = 0; i < 8; ++i)
        #pragma unroll
        for (int j = 0; j < 8; ++j) acc[i][j] = fmaf(a[i], w[j], acc[i][j]);
    }
    if (t < 3) store_tile((t + 1) & 1);   // disjoint from buffer being read
    __syncthreads();
  }

  // epilogue: y1 -> hs (relu + b1), y2 -> global raw
  if (jg < 8) {
    const float4 b1a = *(const float4*)(b1 + jg * 8);
    const float4 b1b = *(const float4*)(b1 + jg * 8 + 4);
    #pragma unroll
    for (int i = 0; i < 8; ++i) {
      const int row = rg * 8 + i;
      *(float4*)&hs[row][jg * 8] = make_float4(
          fmaxf(acc[i][0] + b1a.x, 0.f), fmaxf(acc[i][1] + b1a.y, 0.f),
          fmaxf(acc[i][2] + b1a.z, 0.f), fmaxf(acc[i][3] + b1a.w, 0.f));
      *(float4*)&hs[row][jg * 8 + 4] = make_float4(
          fmaxf(acc[i][4] + b1b.x, 0.f), fmaxf(acc[i][5] + b1b.y, 0.f),
          fmaxf(acc[i][6] + b1b.z, 0.f), fmaxf(acc[i][7] + b1b.w, 0.f));
    }
  } else {
    #pragma unroll
    for (int i = 0; i < 8; ++i) {
      const long row = vb + rg * 8 + i;
      *(float4*)&y2[row * 64 + (jg - 8) * 8] =
          make_float4(acc[i][0], acc[i][1], acc[i][2], acc[i][3]);
      *(float4*)&y2[row * 64 + (jg - 8) * 8 + 4] =
          make_float4(acc[i][4], acc[i][5], acc[i][6], acc[i][7]);
    }
  }
  __syncthreads();

  // vertex layer 2 + sigmoid
  const int jg2 = tid & 7, eg2 = tid >> 3;
  float p[4][8];
  #pragma unroll
  for (int i = 0; i < 4; ++i)
    #pragma unroll
    for (int o = 0; o < 8; ++o) p[i][o] = 0.f;
  #pragma unroll
  for (int jj = 0; jj < 8; ++jj) {
    const float4 w20 = *(const float4*)&W2s[(jg2 * 8 + jj) * 8];
    const float4 w21 = *(const float4*)&W2s[(jg2 * 8 + jj) * 8 + 4];
    const float w2r[8] = {w20.x, w20.y, w20.z, w20.w, w21.x, w21.y, w21.z, w21.w};
    #pragma unroll
    for (int i = 0; i < 4; ++i) {
      const float hv = hs[eg2 * 4 + i][jg2 * 8 + jj];
      #pragma unroll
      for (int o = 0; o < 8; ++o) p[i][o] = fmaf(hv, w2r[o], p[i][o]);
    }
  }
  #pragma unroll
  for (int m = 1; m <= 4; m <<= 1)
    #pragma unroll
    for (int i = 0; i < 4; ++i)
      #pragma unroll
      for (int o = 0; o < 8; ++o) p[i][o] += __shfl_xor(p[i][o], m, 64);

  if (jg2 < 4) {
    const float4 b2a = *(const float4*)b2;
    const float4 b2b = *(const float4*)(b2 + 4);
    const float b2r[8] = {b2a.x, b2a.y, b2a.z, b2a.w, b2b.x, b2b.y, b2b.z, b2b.w};
    const long row = vb + eg2 * 4 + jg2;
    float vout[8];
    #pragma unroll
    for (int o = 0; o < 8; ++o) vout[o] = 1.0f / (1.0f + __expf(-(p[jg2][o] + b2r[o])));
    *(float4*)&fv[row * 8]     = make_float4(vout[0], vout[1], vout[2], vout[3]);
    *(float4*)&fv[row * 8 + 4] = make_float4(vout[4], vout[5], vout[6], vout[7]);
  }
}

// ---- Kernel 2: fused per-graph edge-MLP finish + scatter-min/max + reduce --
// Block g computes fe inline for its 800 edges (8 lanes/edge; butterfly leaves
// the full p[8] in every lane; lane jg scatters feature jg), then reduces and
// atomically accumulates BatchNorm sums. fe never touches global memory.
__global__ __launch_bounds__(256)
void k_reduce(const float* __restrict__ fv, const float* __restrict__ y2,
              const float* __restrict__ pos,
              const int* __restrict__ srcp, const int* __restrict__ dstp,
              const float* __restrict__ We1, const float* __restrict__ be1,
              const float* __restrict__ We2, const float* __restrict__ be2,
              const float* __restrict__ Wd0, const float* __restrict__ bd0,
              const float* __restrict__ Wd1, const float* __restrict__ bd1,
              float* __restrict__ hbuf, float* __restrict__ bnacc) {
  __shared__ unsigned dminS[8 * V_PER];  // plane f at f*V_PER
  __shared__ unsigned dmaxS[8 * V_PER];
  __shared__ float red[256];
  __shared__ float sums[3][8];
  const int tid = threadIdx.x;
  const int g = blockIdx.x;
  const int jg = tid & 7, eslot = tid >> 3;

  for (int i = tid; i < 8 * V_PER; i += 256) {
    dminS[i] = 0x7F800000u;  // +inf (fe > 0 so uint compare == float compare)
    dmaxS[i] = 0u;
  }

  // per-thread invariant edge-MLP params
  float w2[64];  // We2 rows jg*8..jg*8+7
  #pragma unroll
  for (int q = 0; q < 16; ++q)
    *(float4*)&w2[q * 4] = ((const float4*)(We2 + jg * 64))[q];
  const float4 wda = *(const float4*)(We1 + 128 * 64 + jg * 8);
  const float4 wdb = *(const float4*)(We1 + 128 * 64 + jg * 8 + 4);
  const float4 bea = *(const float4*)(be1 + jg * 8);
  const float4 beb = *(const float4*)(be1 + jg * 8 + 4);
  const float wd[8] = {wda.x, wda.y, wda.z, wda.w, wdb.x, wdb.y, wdb.z, wdb.w};
  const float be[8] = {bea.x, bea.y, bea.z, bea.w, beb.x, beb.y, beb.z, beb.w};
  const float be2o = be2[jg];
  __syncthreads();

  const int eb = g * E_PER;
  const int vb = g * V_PER;

  #pragma unroll 2
  for (int pass = 0; pass < E_PER / 32; ++pass) {
    const long e = eb + pass * 32 + eslot;
    const int s = srcp[e], d = dstp[e];
    const float4 a0 = *(const float4*)(y2 + (long)s * 64 + jg * 8);
    const float4 a1 = *(const float4*)(y2 + (long)s * 64 + jg * 8 + 4);
    const float4 c0 = *(const float4*)(y2 + (long)d * 64 + jg * 8);
    const float4 c1 = *(const float4*)(y2 + (long)d * 64 + jg * 8 + 4);
    const float dx = pos[s * 3 + 0] - pos[d * 3 + 0];
    const float dy = pos[s * 3 + 1] - pos[d * 3 + 1];
    const float dz = pos[s * 3 + 2] - pos[d * 3 + 2];
    const float dist = sqrtf(dx * dx + dy * dy + dz * dz);
    const float hh[8] = {a0.x + c0.x, a0.y + c0.y, a0.z + c0.z, a0.w + c0.w,
                         a1.x + c1.x, a1.y + c1.y, a1.z + c1.z, a1.w + c1.w};
    float p[8];
    #pragma unroll
    for (int o = 0; o < 8; ++o) p[o] = 0.f;
    #pragma unroll
    for (int jj = 0; jj < 8; ++jj) {
      const float hv = fmaxf(fmaf(dist, wd[jj], hh[jj] + be[jj]), 0.f);
      #pragma unroll
      for (int o = 0; o < 8; ++o) p[o] = fmaf(hv, w2[jj * 8 + o], p[o]);
    }
    #pragma unroll
    for (int m = 1; m <= 4; m <<= 1)
      #pragma unroll
      for (int o = 0; o < 8; ++o) p[o] += __shfl_xor(p[o], m, 64);
    // lane jg owns feature f = jg; static select of p[jg]
    float pf = p[0];
    #pragma unroll
    for (int o = 1; o < 8; ++o) pf = (jg == o) ? p[o] : pf;
    const float fev = 1.0f / (1.0f + __expf(-(pf + be2o)));
    const unsigned bits = __float_as_uint(fev);
    const int ls = s - vb, ld = d - vb;
    atomicMin(&dminS[jg * V_PER + ls], bits);
    atomicMax(&dmaxS[jg * V_PER + ls], bits);
    atomicMin(&dminS[jg * V_PER + ld], bits);
    atomicMax(&dmaxS[jg * V_PER + ld], bits);
  }
  __syncthreads();

  // per-f sums of fv, dmax, dmin (isolated vertices -> 1.0 both)
  const int f = tid & 7;
  float sfv = 0.f, smin = 0.f, smax = 0.f;
  for (int vv = tid >> 3; vv < V_PER; vv += 32) {
    sfv += fv[(long)(vb + vv) * 8 + f];
    const unsigned mn = dminS[f * V_PER + vv];
    if (mn == 0x7F800000u) { smin += 1.0f; smax += 1.0f; }
    else { smin += __uint_as_float(mn); smax += __uint_as_float(dmaxS[f * V_PER + vv]); }
  }
  red[tid] = sfv; __syncthreads();
  for (int s = 128; s >= 8; s >>= 1) { if (tid < s) red[tid] += red[tid + s]; __syncthreads(); }
  if (tid < 8) sums[0][tid] = red[tid];
  __syncthreads();
  red[tid] = smax; __syncthreads();
  for (int s = 128; s >= 8; s >>= 1) { if (tid < s) red[tid] += red[tid + s]; __syncthreads(); }
  if (tid < 8) sums[1][tid] = red[tid];
  __syncthreads();
  red[tid] = smin; __syncthreads();
  for (int s = 128; s >= 8; s >>= 1) { if (tid < s) red[tid] += red[tid + s]; __syncthreads(); }
  if (tid < 8) sums[2][tid] = red[tid];
  __syncthreads();

  if (tid < 64) {
    const int o = tid;
    const float inv = 1.0f / (float)V_PER;
    float acc = bd0[o];
    #pragma unroll
    for (int ff = 0; ff < 8; ++ff) {
      acc = fmaf(sums[0][ff] * inv, Wd0[(4 * ff + 1) * 64 + o], acc);
      acc = fmaf(sums[1][ff] * inv, Wd0[(4 * ff + 2) * 64 + o], acc);
      acc = fmaf(sums[2][ff] * inv, Wd0[(4 * ff + 3) * 64 + o], acc);
    }
    const float x1 = Wd1[64 + o] + Wd1[128 + o] + Wd1[192 + o] + bd1[o];
    const float hv = acc + x1;
    hbuf[g * 64 + o] = hv;
    atomicAdd(&bnacc[o], hv);             // BN sum
    atomicAdd(&bnacc[64 + o], hv * hv);   // BN sum of squares
  }
}

// ---------------- Kernel 3: BN (from bnacc) + out MLP -----------------------
__global__ __launch_bounds__(256)
void k_out_mlp(const float* __restrict__ hbuf, const float* __restrict__ bnacc,
               const float* __restrict__ gam, const float* __restrict__ bet,
               const float* __restrict__ Wo1, const float* __restrict__ bo1,
               const float* __restrict__ Wo2, const float* __restrict__ bo2,
               float* __restrict__ out) {
  __shared__ float W1s[64 * 64], W2s[64 * 64];
  __shared__ float hn[4][64], t1[4][64];
  __shared__ float mus[64], rstds[64], gs[64], bs[64], b1s[64], b2s[64];
  const int tid = threadIdx.x;
  for (int i = tid; i < 4096; i += 256) { W1s[i] = Wo1[i]; W2s[i] = Wo2[i]; }
  if (tid < 64) {
    const float s = bnacc[tid], s2 = bnacc[64 + tid];
    const float m = s * (1.0f / 512.0f);
    const float var = s2 * (1.0f / 512.0f) - m * m;
    mus[tid] = m; rstds[tid] = rsqrtf(var + 1e-5f);
    gs[tid] = gam[tid]; bs[tid] = bet[tid];
    b1s[tid] = bo1[tid]; b2s[tid] = bo2[tid];
  }
  __syncthreads();
  const int r = tid >> 6, o = tid & 63;
  for (int it = 0; it < 4; ++it) {
    const int row = blockIdx.x * 16 + it * 4 + r;
    hn[r][o] = (hbuf[row * 64 + o] - mus[o]) * rstds[o] * gs[o] + bs[o];
    __syncthreads();
    float a = b1s[o];
    #pragma unroll 8
    for (int i = 0; i < 64; ++i) a = fmaf(hn[r][i], W1s[i * 64 + o], a);
    t1[r][o] = fmaxf(a, 0.f);
    __syncthreads();
    float a2 = b2s[o];
    #pragma unroll 8
    for (int i = 0; i < 64; ++i) a2 = fmaf(t1[r][i], W2s[i * 64 + o], a2);
    out[row * 64 + o] = a2;
    __syncthreads();
  }
}

extern "C" void kernel_launch(void* const* d_in, const int* in_sizes, int n_in,
                              void* d_out, int out_size, void* d_ws, size_t ws_size,
                              hipStream_t stream) {
  const float* x   = (const float*)d_in[0];
  const float* pos = (const float*)d_in[1];
  const int*   ei  = (const int*)d_in[2];
  const float* W1  = (const float*)d_in[6];
  const float* b1  = (const float*)d_in[7];
  const float* W2  = (const float*)d_in[8];
  const float* b2  = (const float*)d_in[9];
  const float* We1 = (const float*)d_in[10];
  const float* be1 = (const float*)d_in[11];
  const float* We2 = (const float*)d_in[12];
  const float* be2 = (const float*)d_in[13];
  const float* Wd0 = (const float*)d_in[14];
  const float* bd0 = (const float*)d_in[15];
  const float* Wd1 = (const float*)d_in[16];
  const float* bd1 = (const float*)d_in[17];
  const float* gam = (const float*)d_in[18];
  const float* bet = (const float*)d_in[19];
  const float* Wo1 = (const float*)d_in[20];
  const float* bo1 = (const float*)d_in[21];
  const float* Wo2 = (const float*)d_in[22];
  const float* bo2 = (const float*)d_in[23];

  const int* srcp = ei;
  const int* dstp = ei + NE;

  float* fv    = (float*)d_ws;               // NV*8
  float* hb    = fv + (size_t)NV * 8;        // NG*64
  float* bnacc = hb + (size_t)NG * 64;       // 128
  float* y2    = bnacc + 128;                // NV*64 (52.4 MB)

  hipMemsetAsync(bnacc, 0, 128 * sizeof(float), stream);
  hipLaunchKernelGGL(k_proj, dim3(NV / BM), dim3(256), 0, stream,
                     x, W1, b1, W2, b2, We1, fv, y2);
  hipLaunchKernelGGL(k_reduce, dim3(NG), dim3(256), 0, stream,
                     fv, y2, pos, srcp, dstp, We1, be1, We2, be2,
                     Wd0, bd0, Wd1, bd1, hb, bnacc);
  hipLaunchKernelGGL(k_out_mlp, dim3(NG / 16), dim3(256), 0, stream,
                     hb, bnacc, gam, bet, Wo1, bo1, Wo2, bo2, (float*)d_out);
}

// Round 9
// 348.382 us; speedup vs baseline: 1.9654x; 1.9654x over previous
//
#include <hip/hip_runtime.h>
#include <math.h>

#define NV 204800
#define NE 409600
#define NG 512
#define V_PER 400
#define E_PER 800

#define BM 128   // rows per block in the projection GEMM
#define KT 32    // k-tile

// Wt column swizzle (float4-granular XOR of word-bit2 with word-bit5).
__device__ __forceinline__ int wswz(int j) { return j ^ (((j >> 5) & 1) << 2); }

// ---- Kernel 1: fused projection GEMM  y = x @ [W1 | We1[0:128]]  ----------
// R6-proven single-buffered version (64 VGPR, no spill). Do NOT add register
// prefetch here: R2 and R7 both spilled (R7: 256 VGPR, 923 MB scratch writes).
__global__ __launch_bounds__(256)
void k_proj(const float* __restrict__ x, const float* __restrict__ W1,
            const float* __restrict__ b1, const float* __restrict__ W2,
            const float* __restrict__ b2, const float* __restrict__ We1,
            float* __restrict__ fv, float* __restrict__ y2) {
  // union: phase1 = xt[32][128] (16KB) + Wt[32][128] (16KB); phase2 = hs[128][65]
  __shared__ __align__(16) char smem[33280];
  float (*xt)[BM] = (float (*)[BM])smem;
  float (*Wt)[BM] = (float (*)[BM])(smem + KT * BM * 4);
  float (*hs)[65] = (float (*)[65])smem;
  __shared__ float W2s[64 * 8];

  const int tid = threadIdx.x;
  const long vb = (long)blockIdx.x * BM;

  if (tid < 128) ((float4*)W2s)[tid] = ((const float4*)W2)[tid];

  const int v = tid >> 1, h = tid & 1;      // staging: 2 threads per row
  const int jg = tid & 15, rg = tid >> 4;   // compute: 16 col-grps x 16 row-grps

  const int wb0 = wswz(jg * 8);
  const int wb1 = wswz(jg * 8 + 4);

  float acc[8][8];
  #pragma unroll
  for (int i = 0; i < 8; ++i)
    #pragma unroll
    for (int j = 0; j < 8; ++j) acc[i][j] = 0.f;

  #pragma unroll 1
  for (int t = 0; t < 4; ++t) {
    { // stage x tile (transposed) and both weight halves (swizzled cols)
      const float4* src = (const float4*)(x + (vb + v) * 128 + t * KT + h * 16);
      const float4 a0 = src[0], a1 = src[1], a2 = src[2], a3 = src[3];
      const int r = h * 16;
      xt[r + 0][v] = a0.x; xt[r + 1][v] = a0.y; xt[r + 2][v] = a0.z; xt[r + 3][v] = a0.w;
      xt[r + 4][v] = a1.x; xt[r + 5][v] = a1.y; xt[r + 6][v] = a1.z; xt[r + 7][v] = a1.w;
      xt[r + 8][v] = a2.x; xt[r + 9][v] = a2.y; xt[r +10][v] = a2.z; xt[r +11][v] = a2.w;
      xt[r +12][v] = a3.x; xt[r +13][v] = a3.y; xt[r +14][v] = a3.z; xt[r +15][v] = a3.w;
      #pragma unroll
      for (int q = 0; q < 2; ++q) {
        const int idx = tid + q * 256;          // 512 float4 per slab
        const int kk = idx >> 4, j4 = idx & 15;
        const float4 wa = ((const float4*)(W1 + t * KT * 64))[idx];
        const float4 wb = ((const float4*)(We1 + t * KT * 64))[idx];
        *(float4*)&Wt[kk][wswz(j4 * 4)] = wa;
        *(float4*)&Wt[kk][wswz(64 + j4 * 4)] = wb;
      }
    }
    __syncthreads();
    #pragma unroll
    for (int kk = 0; kk < KT; ++kk) {
      const float4 av0 = *(const float4*)&xt[kk][rg * 8];
      const float4 av1 = *(const float4*)&xt[kk][rg * 8 + 4];
      const float4 w0 = *(const float4*)&Wt[kk][wb0];
      const float4 w1 = *(const float4*)&Wt[kk][wb1];
      const float a[8] = {av0.x, av0.y, av0.z, av0.w, av1.x, av1.y, av1.z, av1.w};
      const float w[8] = {w0.x, w0.y, w0.z, w0.w, w1.x, w1.y, w1.z, w1.w};
      #pragma unroll
      for (int i = 0; i < 8; ++i)
        #pragma unroll
        for (int j = 0; j < 8; ++j) acc[i][j] = fmaf(a[i], w[j], acc[i][j]);
    }
    __syncthreads();
  }

  // epilogue: y1 -> hs (relu + b1), y2 -> global raw
  if (jg < 8) {
    const float4 b1a = *(const float4*)(b1 + jg * 8);
    const float4 b1b = *(const float4*)(b1 + jg * 8 + 4);
    #pragma unroll
    for (int i = 0; i < 8; ++i) {
      const int row = rg * 8 + i;
      *(float4*)&hs[row][jg * 8] = make_float4(
          fmaxf(acc[i][0] + b1a.x, 0.f), fmaxf(acc[i][1] + b1a.y, 0.f),
          fmaxf(acc[i][2] + b1a.z, 0.f), fmaxf(acc[i][3] + b1a.w, 0.f));
      *(float4*)&hs[row][jg * 8 + 4] = make_float4(
          fmaxf(acc[i][4] + b1b.x, 0.f), fmaxf(acc[i][5] + b1b.y, 0.f),
          fmaxf(acc[i][6] + b1b.z, 0.f), fmaxf(acc[i][7] + b1b.w, 0.f));
    }
  } else {
    #pragma unroll
    for (int i = 0; i < 8; ++i) {
      const long row = vb + rg * 8 + i;
      *(float4*)&y2[row * 64 + (jg - 8) * 8] =
          make_float4(acc[i][0], acc[i][1], acc[i][2], acc[i][3]);
      *(float4*)&y2[row * 64 + (jg - 8) * 8 + 4] =
          make_float4(acc[i][4], acc[i][5], acc[i][6], acc[i][7]);
    }
  }
  __syncthreads();

  // vertex layer 2 + sigmoid
  const int jg2 = tid & 7, eg2 = tid >> 3;
  float p[4][8];
  #pragma unroll
  for (int i = 0; i < 4; ++i)
    #pragma unroll
    for (int o = 0; o < 8; ++o) p[i][o] = 0.f;
  #pragma unroll
  for (int jj = 0; jj < 8; ++jj) {
    const float4 w20 = *(const float4*)&W2s[(jg2 * 8 + jj) * 8];
    const float4 w21 = *(const float4*)&W2s[(jg2 * 8 + jj) * 8 + 4];
    const float w2r[8] = {w20.x, w20.y, w20.z, w20.w, w21.x, w21.y, w21.z, w21.w};
    #pragma unroll
    for (int i = 0; i < 4; ++i) {
      const float hv = hs[eg2 * 4 + i][jg2 * 8 + jj];
      #pragma unroll
      for (int o = 0; o < 8; ++o) p[i][o] = fmaf(hv, w2r[o], p[i][o]);
    }
  }
  #pragma unroll
  for (int m = 1; m <= 4; m <<= 1)
    #pragma unroll
    for (int i = 0; i < 4; ++i)
      #pragma unroll
      for (int o = 0; o < 8; ++o) p[i][o] += __shfl_xor(p[i][o], m, 64);

  if (jg2 < 4) {
    const float4 b2a = *(const float4*)b2;
    const float4 b2b = *(const float4*)(b2 + 4);
    const float b2r[8] = {b2a.x, b2a.y, b2a.z, b2a.w, b2b.x, b2b.y, b2b.z, b2b.w};
    const long row = vb + eg2 * 4 + jg2;
    float vout[8];
    #pragma unroll
    for (int o = 0; o < 8; ++o) vout[o] = 1.0f / (1.0f + __expf(-(p[jg2][o] + b2r[o])));
    *(float4*)&fv[row * 8]     = make_float4(vout[0], vout[1], vout[2], vout[3]);
    *(float4*)&fv[row * 8 + 4] = make_float4(vout[4], vout[5], vout[6], vout[7]);
  }
}

// ---- Kernel 2: fused per-graph edge-MLP finish + scatter-min/max + reduce --
// Block g computes fe inline for its 800 edges (8 lanes/edge; butterfly leaves
// the full p[8] in every lane; lane jg scatters feature jg), then reduces and
// atomically accumulates BatchNorm sums. fe never touches global memory.
__global__ __launch_bounds__(256)
void k_reduce(const float* __restrict__ fv, const float* __restrict__ y2,
              const float* __restrict__ pos,
              const int* __restrict__ srcp, const int* __restrict__ dstp,
              const float* __restrict__ We1, const float* __restrict__ be1,
              const float* __restrict__ We2, const float* __restrict__ be2,
              const float* __restrict__ Wd0, const float* __restrict__ bd0,
              const float* __restrict__ Wd1, const float* __restrict__ bd1,
              float* __restrict__ hbuf, float* __restrict__ bnacc) {
  __shared__ unsigned dminS[8 * V_PER];  // plane f at f*V_PER
  __shared__ unsigned dmaxS[8 * V_PER];
  __shared__ float red[256];
  __shared__ float sums[3][8];
  const int tid = threadIdx.x;
  const int g = blockIdx.x;
  const int jg = tid & 7, eslot = tid >> 3;

  for (int i = tid; i < 8 * V_PER; i += 256) {
    dminS[i] = 0x7F800000u;  // +inf (fe > 0 so uint compare == float compare)
    dmaxS[i] = 0u;
  }

  // per-thread invariant edge-MLP params
  float w2[64];  // We2 rows jg*8..jg*8+7
  #pragma unroll
  for (int q = 0; q < 16; ++q)
    *(float4*)&w2[q * 4] = ((const float4*)(We2 + jg * 64))[q];
  const float4 wda = *(const float4*)(We1 + 128 * 64 + jg * 8);
  const float4 wdb = *(const float4*)(We1 + 128 * 64 + jg * 8 + 4);
  const float4 bea = *(const float4*)(be1 + jg * 8);
  const float4 beb = *(const float4*)(be1 + jg * 8 + 4);
  const float wd[8] = {wda.x, wda.y, wda.z, wda.w, wdb.x, wdb.y, wdb.z, wdb.w};
  const float be[8] = {bea.x, bea.y, bea.z, bea.w, beb.x, beb.y, beb.z, beb.w};
  const float be2o = be2[jg];
  __syncthreads();

  const int eb = g * E_PER;
  const int vb = g * V_PER;

  #pragma unroll 2
  for (int pass = 0; pass < E_PER / 32; ++pass) {
    const long e = eb + pass * 32 + eslot;
    const int s = srcp[e], d = dstp[e];
    const float4 a0 = *(const float4*)(y2 + (long)s * 64 + jg * 8);
    const float4 a1 = *(const float4*)(y2 + (long)s * 64 + jg * 8 + 4);
    const float4 c0 = *(const float4*)(y2 + (long)d * 64 + jg * 8);
    const float4 c1 = *(const float4*)(y2 + (long)d * 64 + jg * 8 + 4);
    const float dx = pos[s * 3 + 0] - pos[d * 3 + 0];
    const float dy = pos[s * 3 + 1] - pos[d * 3 + 1];
    const float dz = pos[s * 3 + 2] - pos[d * 3 + 2];
    const float dist = sqrtf(dx * dx + dy * dy + dz * dz);
    const float hh[8] = {a0.x + c0.x, a0.y + c0.y, a0.z + c0.z, a0.w + c0.w,
                         a1.x + c1.x, a1.y + c1.y, a1.z + c1.z, a1.w + c1.w};
    float p[8];
    #pragma unroll
    for (int o = 0; o < 8; ++o) p[o] = 0.f;
    #pragma unroll
    for (int jj = 0; jj < 8; ++jj) {
      const float hv = fmaxf(fmaf(dist, wd[jj], hh[jj] + be[jj]), 0.f);
      #pragma unroll
      for (int o = 0; o < 8; ++o) p[o] = fmaf(hv, w2[jj * 8 + o], p[o]);
    }
    #pragma unroll
    for (int m = 1; m <= 4; m <<= 1)
      #pragma unroll
      for (int o = 0; o < 8; ++o) p[o] += __shfl_xor(p[o], m, 64);
    // lane jg owns feature f = jg; static select of p[jg]
    float pf = p[0];
    #pragma unroll
    for (int o = 1; o < 8; ++o) pf = (jg == o) ? p[o] : pf;
    const float fev = 1.0f / (1.0f + __expf(-(pf + be2o)));
    const unsigned bits = __float_as_uint(fev);
    const int ls = s - vb, ld = d - vb;
    atomicMin(&dminS[jg * V_PER + ls], bits);
    atomicMax(&dmaxS[jg * V_PER + ls], bits);
    atomicMin(&dminS[jg * V_PER + ld], bits);
    atomicMax(&dmaxS[jg * V_PER + ld], bits);
  }
  __syncthreads();

  // per-f sums of fv, dmax, dmin (isolated vertices -> 1.0 both)
  const int f = tid & 7;
  float sfv = 0.f, smin = 0.f, smax = 0.f;
  for (int vv = tid >> 3; vv < V_PER; vv += 32) {
    sfv += fv[(long)(vb + vv) * 8 + f];
    const unsigned mn = dminS[f * V_PER + vv];
    if (mn == 0x7F800000u) { smin += 1.0f; smax += 1.0f; }
    else { smin += __uint_as_float(mn); smax += __uint_as_float(dmaxS[f * V_PER + vv]); }
  }
  red[tid] = sfv; __syncthreads();
  for (int s = 128; s >= 8; s >>= 1) { if (tid < s) red[tid] += red[tid + s]; __syncthreads(); }
  if (tid < 8) sums[0][tid] = red[tid];
  __syncthreads();
  red[tid] = smax; __syncthreads();
  for (int s = 128; s >= 8; s >>= 1) { if (tid < s) red[tid] += red[tid + s]; __syncthreads(); }
  if (tid < 8) sums[1][tid] = red[tid];
  __syncthreads();
  red[tid] = smin; __syncthreads();
  for (int s = 128; s >= 8; s >>= 1) { if (tid < s) red[tid] += red[tid + s]; __syncthreads(); }
  if (tid < 8) sums[2][tid] = red[tid];
  __syncthreads();

  if (tid < 64) {
    const int o = tid;
    const float inv = 1.0f / (float)V_PER;
    float acc = bd0[o];
    #pragma unroll
    for (int ff = 0; ff < 8; ++ff) {
      acc = fmaf(sums[0][ff] * inv, Wd0[(4 * ff + 1) * 64 + o], acc);
      acc = fmaf(sums[1][ff] * inv, Wd0[(4 * ff + 2) * 64 + o], acc);
      acc = fmaf(sums[2][ff] * inv, Wd0[(4 * ff + 3) * 64 + o], acc);
    }
    const float x1 = Wd1[64 + o] + Wd1[128 + o] + Wd1[192 + o] + bd1[o];
    const float hv = acc + x1;
    hbuf[g * 64 + o] = hv;
    atomicAdd(&bnacc[o], hv);             // BN sum
    atomicAdd(&bnacc[64 + o], hv * hv);   // BN sum of squares
  }
}

// ---------------- Kernel 3: BN (from bnacc) + out MLP -----------------------
__global__ __launch_bounds__(256)
void k_out_mlp(const float* __restrict__ hbuf, const float* __restrict__ bnacc,
               const float* __restrict__ gam, const float* __restrict__ bet,
               const float* __restrict__ Wo1, const float* __restrict__ bo1,
               const float* __restrict__ Wo2, const float* __restrict__ bo2,
               float* __restrict__ out) {
  __shared__ float W1s[64 * 64], W2s[64 * 64];
  __shared__ float hn[4][64], t1[4][64];
  __shared__ float mus[64], rstds[64], gs[64], bs[64], b1s[64], b2s[64];
  const int tid = threadIdx.x;
  for (int i = tid; i < 4096; i += 256) { W1s[i] = Wo1[i]; W2s[i] = Wo2[i]; }
  if (tid < 64) {
    const float s = bnacc[tid], s2 = bnacc[64 + tid];
    const float m = s * (1.0f / 512.0f);
    const float var = s2 * (1.0f / 512.0f) - m * m;
    mus[tid] = m; rstds[tid] = rsqrtf(var + 1e-5f);
    gs[tid] = gam[tid]; bs[tid] = bet[tid];
    b1s[tid] = bo1[tid]; b2s[tid] = bo2[tid];
  }
  __syncthreads();
  const int r = tid >> 6, o = tid & 63;
  for (int it = 0; it < 4; ++it) {
    const int row = blockIdx.x * 16 + it * 4 + r;
    hn[r][o] = (hbuf[row * 64 + o] - mus[o]) * rstds[o] * gs[o] + bs[o];
    __syncthreads();
    float a = b1s[o];
    #pragma unroll 8
    for (int i = 0; i < 64; ++i) a = fmaf(hn[r][i], W1s[i * 64 + o], a);
    t1[r][o] = fmaxf(a, 0.f);
    __syncthreads();
    float a2 = b2s[o];
    #pragma unroll 8
    for (int i = 0; i < 64; ++i) a2 = fmaf(t1[r][i], W2s[i * 64 + o], a2);
    out[row * 64 + o] = a2;
    __syncthreads();
  }
}

extern "C" void kernel_launch(void* const* d_in, const int* in_sizes, int n_in,
                              void* d_out, int out_size, void* d_ws, size_t ws_size,
                              hipStream_t stream) {
  const float* x   = (const float*)d_in[0];
  const float* pos = (const float*)d_in[1];
  const int*   ei  = (const int*)d_in[2];
  const float* W1  = (const float*)d_in[6];
  const float* b1  = (const float*)d_in[7];
  const float* W2  = (const float*)d_in[8];
  const float* b2  = (const float*)d_in[9];
  const float* We1 = (const float*)d_in[10];
  const float* be1 = (const float*)d_in[11];
  const float* We2 = (const float*)d_in[12];
  const float* be2 = (const float*)d_in[13];
  const float* Wd0 = (const float*)d_in[14];
  const float* bd0 = (const float*)d_in[15];
  const float* Wd1 = (const float*)d_in[16];
  const float* bd1 = (const float*)d_in[17];
  const float* gam = (const float*)d_in[18];
  const float* bet = (const float*)d_in[19];
  const float* Wo1 = (const float*)d_in[20];
  const float* bo1 = (const float*)d_in[21];
  const float* Wo2 = (const float*)d_in[22];
  const float* bo2 = (const float*)d_in[23];

  const int* srcp = ei;
  const int* dstp = ei + NE;

  float* fv    = (float*)d_ws;               // NV*8
  float* hb    = fv + (size_t)NV * 8;        // NG*64
  float* bnacc = hb + (size_t)NG * 64;       // 128
  float* y2    = bnacc + 128;                // NV*64 (52.4 MB)

  hipMemsetAsync(bnacc, 0, 128 * sizeof(float), stream);
  hipLaunchKernelGGL(k_proj, dim3(NV / BM), dim3(256), 0, stream,
                     x, W1, b1, W2, b2, We1, fv, y2);
  hipLaunchKernelGGL(k_reduce, dim3(NG), dim3(256), 0, stream,
                     fv, y2, pos, srcp, dstp, We1, be1, We2, be2,
                     Wd0, bd0, Wd1, bd1, hb, bnacc);
  hipLaunchKernelGGL(k_out_mlp, dim3(NG / 16), dim3(256), 0, stream,
                     hb, bnacc, gam, bet, Wo1, bo1, Wo2, bo2, (float*)d_out);
}